// Round 1
// baseline (865.190 us; speedup 1.0000x reference)
//
#include <hip/hip_runtime.h>

#define M_ROWS 17664   // B*T = 64*276
#define K_CODES 8192
#define D_DIM 256
#define N_ELEM 4521984 // M_ROWS * 256

#define BM 128
#define BN 128
#define BK 32
#define LDT 132        // padded LDS row: 132%4==0 (16B align), 132%32==4 (bank spread)

// ---------------------------------------------------------------------------
// Exact replication of numpy pairwise sum of squares for a 256-wide row:
// pairwise(a,256) = pairwise(a,128) + pairwise(a+128,128); each 128-block uses
// 8 accumulators r[j] += a[i+j] and combines ((r0+r1)+(r2+r3))+((r4+r5)+(r6+r7)).
// __fmul_rn/__fadd_rn prevent FMA contraction (must match np's mul-then-add).
// ---------------------------------------------------------------------------
__global__ void rowsq_kernel(const float* __restrict__ X,
                             float* __restrict__ out, int rows) {
    int r = blockIdx.x * blockDim.x + threadIdx.x;
    if (r >= rows) return;
    const float* p = X + (size_t)r * D_DIM;
    float half_sum[2];
#pragma unroll
    for (int h = 0; h < 2; ++h) {
        const float* q = p + h * 128;
        float acc[8];
#pragma unroll
        for (int j = 0; j < 8; ++j) acc[j] = __fmul_rn(q[j], q[j]);
        for (int i = 8; i < 128; i += 8) {
#pragma unroll
            for (int j = 0; j < 8; ++j)
                acc[j] = __fadd_rn(acc[j], __fmul_rn(q[i + j], q[i + j]));
        }
        float s01 = __fadd_rn(acc[0], acc[1]);
        float s23 = __fadd_rn(acc[2], acc[3]);
        float s45 = __fadd_rn(acc[4], acc[5]);
        float s67 = __fadd_rn(acc[6], acc[7]);
        half_sum[h] = __fadd_rn(__fadd_rn(s01, s23), __fadd_rn(s45, s67));
    }
    out[r] = __fadd_rn(half_sum[0], half_sum[1]);
}

__global__ void init_kernel(unsigned long long* __restrict__ packed,
                            float* __restrict__ loss_acc) {
    int i = blockIdx.x * blockDim.x + threadIdx.x;
    if (i < M_ROWS) packed[i] = 0xFFFFFFFFFFFFFFFFull;
    if (i == 0) loss_acc[0] = 0.0f;
}

// ---------------------------------------------------------------------------
// fp32 GEMM (dot products) + fused quantized-distance argmin.
// d = fl(fl(a_row + b_col) - 2*dot)  -- matches numpy's rounding structure.
// Packed (d_bits<<32 | col) atomicMin implements argmin with lowest-index ties.
// ---------------------------------------------------------------------------
__global__ __launch_bounds__(256) void gemm_argmin_kernel(
    const float* __restrict__ Z, const float* __restrict__ CB,
    const float* __restrict__ asum, const float* __restrict__ bsum,
    unsigned long long* __restrict__ packed) {
    __shared__ float As[BK][LDT];
    __shared__ float Bs[BK][LDT];

    const int bid = blockIdx.x;
    const int bm = bid >> 6;   // 64 N-tiles
    const int bn = bid & 63;
    const int m0 = bm * BM, n0 = bn * BN;
    const int t = threadIdx.x;
    const int ty = t >> 4, tx = t & 15;

    float acc[8][8];
#pragma unroll
    for (int i = 0; i < 8; ++i)
#pragma unroll
        for (int j = 0; j < 8; ++j) acc[i][j] = 0.0f;

    for (int k0 = 0; k0 < D_DIM; k0 += BK) {
#pragma unroll
        for (int i = 0; i < 4; ++i) {
            int idx = t + i * 256;      // 0..1023
            int row = idx >> 3;         // 0..127
            int kq = idx & 7;           // 0..7 (float4 chunk within BK)
            const float4 av = *(const float4*)(Z + (size_t)(m0 + row) * D_DIM + k0 + kq * 4);
            As[kq * 4 + 0][row] = av.x; As[kq * 4 + 1][row] = av.y;
            As[kq * 4 + 2][row] = av.z; As[kq * 4 + 3][row] = av.w;
            const float4 bv = *(const float4*)(CB + (size_t)(n0 + row) * D_DIM + k0 + kq * 4);
            Bs[kq * 4 + 0][row] = bv.x; Bs[kq * 4 + 1][row] = bv.y;
            Bs[kq * 4 + 2][row] = bv.z; Bs[kq * 4 + 3][row] = bv.w;
        }
        __syncthreads();
#pragma unroll
        for (int k = 0; k < BK; ++k) {
            float af[8], bf[8];
            *(float4*)(af)     = *(const float4*)(&As[k][ty * 4]);
            *(float4*)(af + 4) = *(const float4*)(&As[k][64 + ty * 4]);
            *(float4*)(bf)     = *(const float4*)(&Bs[k][tx * 4]);
            *(float4*)(bf + 4) = *(const float4*)(&Bs[k][64 + tx * 4]);
#pragma unroll
            for (int i = 0; i < 8; ++i)
#pragma unroll
                for (int j = 0; j < 8; ++j)
                    acc[i][j] = __builtin_fmaf(af[i], bf[j], acc[i][j]);
        }
        __syncthreads();
    }

    // epilogue: quantized distance + per-row argmin
    float ar[8], bc[8];
    int rowIdx[8], colIdx[8];
#pragma unroll
    for (int i = 0; i < 8; ++i) {
        rowIdx[i] = (i < 4) ? (4 * ty + i) : (64 + 4 * ty + (i - 4));
        ar[i] = asum[m0 + rowIdx[i]];
    }
#pragma unroll
    for (int j = 0; j < 8; ++j) {
        colIdx[j] = (j < 4) ? (4 * tx + j) : (64 + 4 * tx + (j - 4));
        bc[j] = bsum[n0 + colIdx[j]];
    }
#pragma unroll
    for (int i = 0; i < 8; ++i) {
        unsigned long long best = 0xFFFFFFFFFFFFFFFFull;
#pragma unroll
        for (int j = 0; j < 8; ++j) {
            float ts = __fadd_rn(ar[i], bc[j]);
            float d = __fsub_rn(ts, __fmul_rn(2.0f, acc[i][j]));
            unsigned long long p =
                ((unsigned long long)__float_as_uint(d) << 32) |
                (unsigned)(n0 + colIdx[j]);
            best = (p < best) ? p : best;
        }
        // butterfly min across the 16-lane column group (lanes share ty)
#pragma unroll
        for (int m = 1; m <= 8; m <<= 1) {
            unsigned lo = (unsigned)best;
            unsigned hi = (unsigned)(best >> 32);
            lo = __shfl_xor(lo, m);
            hi = __shfl_xor(hi, m);
            unsigned long long o = ((unsigned long long)hi << 32) | lo;
            best = (o < best) ? o : best;
        }
        if (tx == 0) atomicMin(&packed[m0 + rowIdx[i]], best);
    }
}

// ---------------------------------------------------------------------------
// Gather winning code, write z_q_st = fl(z + fl(c - z)) (bit-exact vs numpy),
// write min_idx as float, accumulate loss sum.
// ---------------------------------------------------------------------------
__global__ __launch_bounds__(256) void finalize_kernel(
    const float* __restrict__ Z, const float* __restrict__ CB,
    const unsigned long long* __restrict__ packed,
    float* __restrict__ out, float* __restrict__ loss_acc) {
    float* out_zq = out + 2;
    float* out_idx = out + 2 + (size_t)N_ELEM;
    const int lane = threadIdx.x & 63;
    const int wid = (blockIdx.x * blockDim.x + threadIdx.x) >> 6;
    const int nw = (gridDim.x * blockDim.x) >> 6;
    float lsum = 0.0f;
    for (int row = wid; row < M_ROWS; row += nw) {
        unsigned long long pk = packed[row];
        unsigned idx = (unsigned)(pk & 0xFFFFFFFFull);
        if (lane == 0) out_idx[row] = (float)idx;
        const float4 zv = *(const float4*)(Z + (size_t)row * D_DIM + lane * 4);
        const float4 cv = *(const float4*)(CB + (size_t)idx * D_DIM + lane * 4);
        float d0 = __fsub_rn(cv.x, zv.x);
        float d1 = __fsub_rn(cv.y, zv.y);
        float d2 = __fsub_rn(cv.z, zv.z);
        float d3 = __fsub_rn(cv.w, zv.w);
        float2 o0 = make_float2(__fadd_rn(zv.x, d0), __fadd_rn(zv.y, d1));
        float2 o1 = make_float2(__fadd_rn(zv.z, d2), __fadd_rn(zv.w, d3));
        *(float2*)(out_zq + (size_t)row * D_DIM + lane * 4) = o0;
        *(float2*)(out_zq + (size_t)row * D_DIM + lane * 4 + 2) = o1;
        lsum += d0 * d0 + d1 * d1 + d2 * d2 + d3 * d3;
    }
    // wave + block reduce, one atomicAdd per block
#pragma unroll
    for (int m = 1; m < 64; m <<= 1) lsum += __shfl_xor(lsum, m);
    __shared__ float red[4];
    if (lane == 0) red[threadIdx.x >> 6] = lsum;
    __syncthreads();
    if (threadIdx.x == 0) {
        float s = ((red[0] + red[1]) + (red[2] + red[3]));
        atomicAdd(loss_acc, s);
    }
}

__global__ void write_losses(const float* __restrict__ loss_acc,
                             float* __restrict__ out) {
    float l = __fdiv_rn(loss_acc[0], (float)N_ELEM);
    out[0] = l;   // loss_vq
    out[1] = l;   // loss_commit (identical forward value)
}

extern "C" void kernel_launch(void* const* d_in, const int* in_sizes, int n_in,
                              void* d_out, int out_size, void* d_ws, size_t ws_size,
                              hipStream_t stream) {
    const float* Z = (const float*)d_in[0];    // [17664, 256]
    const float* CB = (const float*)d_in[1];   // [8192, 256]
    float* out = (float*)d_out;
    char* ws = (char*)d_ws;

    float* asum = (float*)ws;                                   // 17664 f32
    float* bsum = (float*)(ws + (size_t)M_ROWS * 4);            // 8192 f32
    unsigned long long* packed =
        (unsigned long long*)(ws + (size_t)M_ROWS * 4 + (size_t)K_CODES * 4); // 17664 u64
    float* loss_acc =
        (float*)(ws + (size_t)M_ROWS * 4 + (size_t)K_CODES * 4 + (size_t)M_ROWS * 8);

    hipLaunchKernelGGL(init_kernel, dim3((M_ROWS + 255) / 256), dim3(256), 0, stream,
                       packed, loss_acc);
    hipLaunchKernelGGL(rowsq_kernel, dim3((M_ROWS + 255) / 256), dim3(256), 0, stream,
                       Z, asum, M_ROWS);
    hipLaunchKernelGGL(rowsq_kernel, dim3((K_CODES + 255) / 256), dim3(256), 0, stream,
                       CB, bsum, K_CODES);
    hipLaunchKernelGGL(gemm_argmin_kernel, dim3((M_ROWS / BM) * (K_CODES / BN)),
                       dim3(256), 0, stream, Z, CB, asum, bsum, packed);
    hipLaunchKernelGGL(finalize_kernel, dim3(512), dim3(256), 0, stream,
                       Z, CB, packed, out, loss_acc);
    hipLaunchKernelGGL(write_losses, dim3(1), dim3(1), 0, stream, loss_acc, out);
}